// Round 6
// baseline (157.605 us; speedup 1.0000x reference)
//
#include <hip/hip_runtime.h>
#include <math.h>

// DotProductAttention B=64,S=1024,D=64 fp32, bf16-MFMA flash attention.
// Round 5: ZERO-BARRIER wave-independent flash. Each wave owns 32 queries
// (2 x 16-row bands) of one batch; no __syncthreads anywhere. K staged into
// a wave-PRIVATE LDS region (coalesced dwordx4 global reads, b128 LDS
// writes, one-tile register prefetch so global latency overlaps compute).
// V read direct from global (4-row x 64B coalesced pattern, L2-hot: 32
// waves/batch reuse it). P -> wave-private Ps LDS round-trip. In-order
// per-wave LDS makes single-buffer K safe (reads of tile it precede
// overwrite by tile it+1 in program order). exp2-domain softmax, trunc
// bf16 packs. LDS/block = 14.3 KB -> 4 blocks/CU; 1024 blocks x 128 thr.

#define BATCH 64
#define SEQ   1024
#define DIM   64
#define WQ    32            // queries per wave (2 bands of 16)
#define BC    32            // keys per iteration
#define NKT   (SEQ / BC)    // 32
#define KSTR  72            // Ks row stride bf16 (36 dwords === 4 mod 32)
#define PSTR  40            // Ps row stride bf16 (20 dwords === 20 mod 32)
#define QSCALE 0.18033688011112442f   // 0.125 * log2(e)
#define MASKED -1.0e6f

typedef __attribute__((ext_vector_type(8))) short bf16x8;
typedef __attribute__((ext_vector_type(4))) float f32x4;

__device__ __forceinline__ uint pack2_trunc(float lo, float hi) {
    return __builtin_amdgcn_perm(__float_as_uint(hi), __float_as_uint(lo), 0x07060302);
}
__device__ __forceinline__ ushort f2bf_rne(float x) {
    uint u = __float_as_uint(x);
    return (ushort)((u + 0x7fffu + ((u >> 16) & 1u)) >> 16);
}

__global__ __launch_bounds__(128, 2) void attn_waveflash(
    const float* __restrict__ q, const float* __restrict__ k,
    const float* __restrict__ v, const int* __restrict__ valid_lens,
    float* __restrict__ out)
{
    __shared__ ushort Ks[2][BC * KSTR];   // per-wave private: 4608 B each
    __shared__ ushort Ps[2][WQ * PSTR];   // per-wave private: 2560 B each

    const int t    = threadIdx.x;
    const int wv   = t >> 6;           // wave id in block (0,1)
    const int wl   = t & 63;
    const int QD   = wl >> 4;          // quad 0..3
    const int li   = wl & 15;          // lane-in-quad

    const int gw = blockIdx.x * 2 + wv;        // global wave id, 0..2047
    const int b  = gw >> 5;                    // 32 waves per batch
    const int q0 = (gw & 31) * WQ;
    const int vl = valid_lens[b];
    const size_t boff = (size_t)b * SEQ * DIM;

    ushort* ks = Ks[wv];
    ushort* ps = Ps[wv];

    // ---- Q fragments (B-operand), pre-scaled, RNE ----
    bf16x8 qb[2][2];   // [band][d-half]
    #pragma unroll
    for (int band = 0; band < 2; band++) {
        const float* qrow = q + boff + (size_t)(q0 + band * 16 + li) * DIM + QD * 8;
        #pragma unroll
        for (int h = 0; h < 2; h++) {
            float4 a = *(const float4*)(qrow + h * 32);
            float4 c = *(const float4*)(qrow + h * 32 + 4);
            union { bf16x8 v; ushort u[8]; } tmp;
            tmp.u[0] = f2bf_rne(a.x * QSCALE);
            tmp.u[1] = f2bf_rne(a.y * QSCALE);
            tmp.u[2] = f2bf_rne(a.z * QSCALE);
            tmp.u[3] = f2bf_rne(a.w * QSCALE);
            tmp.u[4] = f2bf_rne(c.x * QSCALE);
            tmp.u[5] = f2bf_rne(c.y * QSCALE);
            tmp.u[6] = f2bf_rne(c.z * QSCALE);
            tmp.u[7] = f2bf_rne(c.w * QSCALE);
            qb[band][h] = tmp.v;
        }
    }

    const int it_max = (vl == 0) ? NKT : ((vl + BC - 1) / BC);

    // ---- K tile prefetch: lane covers row wl>>1, 32 cols at (wl&1)*32 ----
    const int krow = wl >> 1;
    const int kcol = (wl & 1) * 32;
    float4 kpf[8];
    auto load_k = [&](int it) {
        const float4* kg = (const float4*)(k + boff + (size_t)it * BC * DIM);
        #pragma unroll
        for (int i = 0; i < 8; i++)
            kpf[i] = kg[krow * 16 + (wl & 1) * 8 + i];
    };
    auto stage_k = [&]() {
        #pragma unroll
        for (int j = 0; j < 4; j++) {
            uint4 w;
            w.x = pack2_trunc(kpf[2 * j].x, kpf[2 * j].y);
            w.y = pack2_trunc(kpf[2 * j].z, kpf[2 * j].w);
            w.z = pack2_trunc(kpf[2 * j + 1].x, kpf[2 * j + 1].y);
            w.w = pack2_trunc(kpf[2 * j + 1].z, kpf[2 * j + 1].w);
            *(uint4*)&ks[krow * KSTR + kcol + j * 8] = w;   // b128
        }
    };

    float m_run[2] = {-INFINITY, -INFINITY};
    float l_run[2] = {0.f, 0.f};
    f32x4 acc[2][4];   // [band][dt]
    #pragma unroll
    for (int band = 0; band < 2; band++)
        #pragma unroll
        for (int dt = 0; dt < 4; dt++) acc[band][dt] = (f32x4){0.f, 0.f, 0.f, 0.f};

    load_k(0);
    stage_k();
    if (it_max > 1) load_k(1);

    for (int it = 0; it < it_max; it++) {
        // 1. A-frag reads of tile `it` (in-order LDS: safe before overwrite)
        bf16x8 ka[2][2];
        #pragma unroll
        for (int kt = 0; kt < 2; kt++)
            #pragma unroll
            for (int h = 0; h < 2; h++)
                ka[kt][h] = *(const bf16x8*)&ks[(kt * 16 + li) * KSTR + h * 32 + QD * 8];

        // 2. stage tile it+1 from prefetch regs (overwrites after reads issue)
        if (it + 1 < it_max) stage_k();
        // 3. issue global prefetch of tile it+2
        if (it + 2 < it_max) load_k(it + 2);

        // 4. issue V loads for tile `it` (direct global, coalesced 4-row)
        const float* vg = v + boff + (size_t)it * BC * DIM;
        float vf[4][8];
        #pragma unroll
        for (int dt = 0; dt < 4; dt++)
            #pragma unroll
            for (int j = 0; j < 8; j++)
                vf[dt][j] = vg[(size_t)(QD * 8 + j) * DIM + dt * 16 + li];

        // 5. S^T = K x Q^T : rows = keys (QD*4+r), cols = queries (li)
        f32x4 sc[2][2];   // [kt][band]
        #pragma unroll
        for (int kt = 0; kt < 2; kt++)
            #pragma unroll
            for (int band = 0; band < 2; band++) {
                f32x4 c = (f32x4){0.f, 0.f, 0.f, 0.f};
                c = __builtin_amdgcn_mfma_f32_16x16x32_bf16(ka[kt][0], qb[band][0], c, 0, 0, 0);
                c = __builtin_amdgcn_mfma_f32_16x16x32_bf16(ka[kt][1], qb[band][1], c, 0, 0, 0);
                sc[kt][band] = c;
            }

        // mask
        const int kbase = it * BC;
        if (kbase + BC > vl) {
            #pragma unroll
            for (int kt = 0; kt < 2; kt++) {
                #pragma unroll
                for (int r = 0; r < 4; r++) {
                    int key = kbase + kt * 16 + QD * 4 + r;
                    if (key >= vl) { sc[kt][0][r] = MASKED; sc[kt][1][r] = MASKED; }
                }
            }
        }

        // online softmax per band (exp2 domain)
        #pragma unroll
        for (int band = 0; band < 2; band++) {
            float mt = -INFINITY;
            #pragma unroll
            for (int kt = 0; kt < 2; kt++)
                #pragma unroll
                for (int r = 0; r < 4; r++) mt = fmaxf(mt, sc[kt][band][r]);
            mt = fmaxf(mt, __shfl_xor(mt, 16, 64));
            mt = fmaxf(mt, __shfl_xor(mt, 32, 64));
            float mn = fmaxf(m_run[band], mt);
            float alpha = exp2f(m_run[band] - mn);
            m_run[band] = mn;

            float ls = 0.f;
            #pragma unroll
            for (int kt = 0; kt < 2; kt++) {
                float p0 = exp2f(sc[kt][band][0] - mn);
                float p1 = exp2f(sc[kt][band][1] - mn);
                float p2 = exp2f(sc[kt][band][2] - mn);
                float p3 = exp2f(sc[kt][band][3] - mn);
                ls += (p0 + p1) + (p2 + p3);
                uint2 w;
                w.x = pack2_trunc(p0, p1);
                w.y = pack2_trunc(p2, p3);
                *(uint2*)&ps[(band * 16 + li) * PSTR + kt * 16 + QD * 4] = w;
            }
            ls += __shfl_xor(ls, 16, 64);
            ls += __shfl_xor(ls, 32, 64);
            l_run[band] = l_run[band] * alpha + ls;

            float a0 = __shfl(alpha, QD * 4 + 0, 64);
            float a1 = __shfl(alpha, QD * 4 + 1, 64);
            float a2 = __shfl(alpha, QD * 4 + 2, 64);
            float a3 = __shfl(alpha, QD * 4 + 3, 64);
            #pragma unroll
            for (int dt = 0; dt < 4; dt++) {
                acc[band][dt][0] *= a0; acc[band][dt][1] *= a1;
                acc[band][dt][2] *= a2; acc[band][dt][3] *= a3;
            }
        }

        // 6. PV: pack V frags from globals, P via wave-private LDS round-trip
        bf16x8 pa[2];
        #pragma unroll
        for (int band = 0; band < 2; band++)
            pa[band] = *(const bf16x8*)&ps[(band * 16 + li) * PSTR + QD * 8];
        #pragma unroll
        for (int dt = 0; dt < 4; dt++) {
            union { bf16x8 v; uint u[4]; } vb;
            vb.u[0] = pack2_trunc(vf[dt][0], vf[dt][1]);
            vb.u[1] = pack2_trunc(vf[dt][2], vf[dt][3]);
            vb.u[2] = pack2_trunc(vf[dt][4], vf[dt][5]);
            vb.u[3] = pack2_trunc(vf[dt][6], vf[dt][7]);
            #pragma unroll
            for (int band = 0; band < 2; band++)
                acc[band][dt] = __builtin_amdgcn_mfma_f32_16x16x32_bf16(pa[band], vb.v, acc[band][dt], 0, 0, 0);
        }
    }

    // ---- epilogue ----
    float* ob = out + boff + (size_t)q0 * DIM;
    #pragma unroll
    for (int band = 0; band < 2; band++) {
        float invl = 1.0f / l_run[band];
        float i0 = __shfl(invl, QD * 4 + 0, 64);
        float i1 = __shfl(invl, QD * 4 + 1, 64);
        float i2 = __shfl(invl, QD * 4 + 2, 64);
        float i3 = __shfl(invl, QD * 4 + 3, 64);
        const int rbase = band * 16 + QD * 4;
        #pragma unroll
        for (int dt = 0; dt < 4; dt++) {
            int col = dt * 16 + li;
            ob[(size_t)(rbase + 0) * DIM + col] = acc[band][dt][0] * i0;
            ob[(size_t)(rbase + 1) * DIM + col] = acc[band][dt][1] * i1;
            ob[(size_t)(rbase + 2) * DIM + col] = acc[band][dt][2] * i2;
            ob[(size_t)(rbase + 3) * DIM + col] = acc[band][dt][3] * i3;
        }
    }
}

extern "C" void kernel_launch(void* const* d_in, const int* in_sizes, int n_in,
                              void* d_out, int out_size, void* d_ws, size_t ws_size,
                              hipStream_t stream) {
    const float* q = (const float*)d_in[0];
    const float* k = (const float*)d_in[1];
    const float* v = (const float*)d_in[2];
    const int* valid_lens = (const int*)d_in[3];
    float* out = (float*)d_out;

    attn_waveflash<<<dim3(BATCH * (SEQ / WQ) / 2), dim3(128), 0, stream>>>(
        q, k, v, valid_lens, out);
}

// Round 7
// 132.567 us; speedup vs baseline: 1.1889x; 1.1889x over previous
//
#include <hip/hip_runtime.h>
#include <math.h>

// DotProductAttention B=64,S=1024,D=64 fp32, bf16-MFMA flash attention.
// Round 6: kill the barrier-drain stall. r2's "stage; load; barrier" order
// forces s_waitcnt vmcnt(0) on JUST-issued prefetch loads at every barrier
// (the m97 plateau mechanism). New loop: ONE barrier per iteration; global
// loads issued right AFTER the barrier (a full compute phase to land);
// staging into the OTHER LDS buffer at iteration END (vmcnt wait ~free);
// barrier only drains LDS ops. BC=32 double-buffered K/V + Ps = 24 KB
// -> 2 blocks/CU (64 KiB co-residency law, r1-r3 measured). Keeps r2's
// batch-major XCD locality (FETCH 17 MB). Q frags in registers, exp2
// softmax, perm-truncation bf16 packs.

#define BATCH 64
#define SEQ   1024
#define DIM   64
#define BQ    64            // queries per block (4 waves x 16)
#define BC    32            // keys per iteration
#define NKT   (SEQ / BC)    // 32
#define KSTR  72            // Ks row stride bf16 (36 dwords === 4 mod 32)
#define VSTR  40            // Vt row stride bf16 (20 dwords)
#define PSTR  40            // Ps row stride bf16
#define QSCALE 0.18033688011112442f   // 0.125 * log2(e)
#define MASKED -1.0e6f

typedef __attribute__((ext_vector_type(8))) short bf16x8;
typedef __attribute__((ext_vector_type(4))) float f32x4;

__device__ __forceinline__ uint pack2_trunc(float lo, float hi) {
    return __builtin_amdgcn_perm(__float_as_uint(hi), __float_as_uint(lo), 0x07060302);
}
__device__ __forceinline__ ushort f2bf_rne(float x) {
    uint u = __float_as_uint(x);
    return (ushort)((u + 0x7fffu + ((u >> 16) & 1u)) >> 16);
}

__global__ __launch_bounds__(256, 2) void attn_mfma_flash6(
    const float* __restrict__ q, const float* __restrict__ k,
    const float* __restrict__ v, const int* __restrict__ valid_lens,
    float* __restrict__ out)
{
    __shared__ ushort Ks[2][BC * KSTR];   // 2 x 4608 B  [buf][key][d]
    __shared__ ushort Vt[2][DIM * VSTR];  // 2 x 5120 B  [buf][d][key]
    __shared__ ushort Ps[BQ * PSTR];      //     5120 B  [query][key] wave-private

    const int t    = threadIdx.x;
    const int wave = t >> 6;
    const int wl   = t & 63;
    const int QD   = wl >> 4;
    const int li   = wl & 15;
    // same-batch blocks share blockIdx mod 8 -> same XCD slot (L2 locality)
    const int b    = blockIdx.x & 63;
    const int q0   = (blockIdx.x >> 6) * BQ;
    const int vl   = valid_lens[b];
    const size_t boff = (size_t)b * SEQ * DIM;

    // ---- Q fragments into registers (B-operand), pre-scaled ----
    bf16x8 qb[2];
    {
        const float* qrow = q + boff + (size_t)(q0 + wave * 16 + li) * DIM + QD * 8;
        #pragma unroll
        for (int h = 0; h < 2; h++) {
            float4 a = *(const float4*)(qrow + h * 32);
            float4 c = *(const float4*)(qrow + h * 32 + 4);
            union { bf16x8 v; ushort u[8]; } tmp;
            tmp.u[0] = f2bf_rne(a.x * QSCALE);
            tmp.u[1] = f2bf_rne(a.y * QSCALE);
            tmp.u[2] = f2bf_rne(a.z * QSCALE);
            tmp.u[3] = f2bf_rne(a.w * QSCALE);
            tmp.u[4] = f2bf_rne(c.x * QSCALE);
            tmp.u[5] = f2bf_rne(c.y * QSCALE);
            tmp.u[6] = f2bf_rne(c.z * QSCALE);
            tmp.u[7] = f2bf_rne(c.w * QSCALE);
            qb[h] = tmp.v;
        }
    }

    const int it_max = (vl == 0) ? NKT : ((vl + BC - 1) / BC);

    float4 kf[2];     // K tile prefetch: 2 coalesced float4/thread
    float  vf[8];     // V tile prefetch: d=wl, keys wave*8..+7 (coalesced)

    auto load_tile = [&](int it) {
        const float4* kg = (const float4*)(k + boff + (size_t)it * BC * DIM);
        kf[0] = kg[t];
        kf[1] = kg[t + 256];
        const float* vgf = v + boff + (size_t)it * BC * DIM;
        #pragma unroll
        for (int j = 0; j < 8; j++)
            vf[j] = vgf[(size_t)(wave * 8 + j) * DIM + wl];
    };
    auto stage = [&](int pb) {
        #pragma unroll
        for (int i = 0; i < 2; i++) {
            int idx = t + 256 * i;
            int row = idx >> 4, c4 = idx & 15;
            uint2 w;
            w.x = pack2_trunc(kf[i].x, kf[i].y);
            w.y = pack2_trunc(kf[i].z, kf[i].w);
            *(uint2*)&Ks[pb][row * KSTR + c4 * 4] = w;
        }
        uint4 wv;
        wv.x = pack2_trunc(vf[0], vf[1]);
        wv.y = pack2_trunc(vf[2], vf[3]);
        wv.z = pack2_trunc(vf[4], vf[5]);
        wv.w = pack2_trunc(vf[6], vf[7]);
        *(uint4*)&Vt[pb][wl * VSTR + wave * 8] = wv;   // b128
    };

    float m_run = -INFINITY, l_run = 0.f;
    f32x4 acc[4];
    #pragma unroll
    for (int dt = 0; dt < 4; dt++) acc[dt] = (f32x4){0.f, 0.f, 0.f, 0.f};

    // prologue: tile 0 staged into buf 0
    load_tile(0);
    stage(0);

    for (int it = 0; it < it_max; it++) {
        const int p = it & 1;
        __syncthreads();   // staged tile `it` (buf p) visible; drains LDS only

        // ---- fragment reads of tile `it` from buf p ----
        bf16x8 ka[2][2], vb[4];
        #pragma unroll
        for (int kt = 0; kt < 2; kt++) {
            ka[kt][0] = *(const bf16x8*)&Ks[p][(kt * 16 + li) * KSTR + QD * 8];
            ka[kt][1] = *(const bf16x8*)&Ks[p][(kt * 16 + li) * KSTR + 32 + QD * 8];
        }
        #pragma unroll
        for (int dt = 0; dt < 4; dt++)
            vb[dt] = *(const bf16x8*)&Vt[p][(dt * 16 + li) * VSTR + QD * 8];

        // ---- issue next tile's global loads NOW (whole compute phase to land)
        if (it + 1 < it_max) load_tile(it + 1);

        // ---- S^T = K x Q^T : rows = keys (QD*4+r), cols = queries (li) ----
        f32x4 sc[2];
        #pragma unroll
        for (int kt = 0; kt < 2; kt++) {
            f32x4 c = (f32x4){0.f, 0.f, 0.f, 0.f};
            c = __builtin_amdgcn_mfma_f32_16x16x32_bf16(ka[kt][0], qb[0], c, 0, 0, 0);
            c = __builtin_amdgcn_mfma_f32_16x16x32_bf16(ka[kt][1], qb[1], c, 0, 0, 0);
            sc[kt] = c;
        }

        // ---- mask (boundary/invalid tiles only) ----
        const int kbase = it * BC;
        if (kbase + BC > vl) {
            #pragma unroll
            for (int kt = 0; kt < 2; kt++)
                #pragma unroll
                for (int r = 0; r < 4; r++) {
                    int key = kbase + kt * 16 + QD * 4 + r;
                    if (key >= vl) sc[kt][r] = MASKED;
                }
        }

        // ---- online softmax, exp2 domain (row = query = li) ----
        float mt = -INFINITY;
        #pragma unroll
        for (int kt = 0; kt < 2; kt++)
            #pragma unroll
            for (int r = 0; r < 4; r++) mt = fmaxf(mt, sc[kt][r]);
        mt = fmaxf(mt, __shfl_xor(mt, 16, 64));
        mt = fmaxf(mt, __shfl_xor(mt, 32, 64));
        float mn = fmaxf(m_run, mt);
        float alpha = exp2f(m_run - mn);
        m_run = mn;

        float ls = 0.f;
        #pragma unroll
        for (int kt = 0; kt < 2; kt++) {
            float p0 = exp2f(sc[kt][0] - mn);
            float p1 = exp2f(sc[kt][1] - mn);
            float p2 = exp2f(sc[kt][2] - mn);
            float p3 = exp2f(sc[kt][3] - mn);
            ls += (p0 + p1) + (p2 + p3);
            uint2 w;
            w.x = pack2_trunc(p0, p1);
            w.y = pack2_trunc(p2, p3);
            *(uint2*)&Ps[(wave * 16 + li) * PSTR + kt * 16 + QD * 4] = w;
        }
        ls += __shfl_xor(ls, 16, 64);
        ls += __shfl_xor(ls, 32, 64);
        l_run = l_run * alpha + ls;

        float a0 = __shfl(alpha, QD * 4 + 0, 64);
        float a1 = __shfl(alpha, QD * 4 + 1, 64);
        float a2 = __shfl(alpha, QD * 4 + 2, 64);
        float a3 = __shfl(alpha, QD * 4 + 3, 64);
        #pragma unroll
        for (int dt = 0; dt < 4; dt++) {
            acc[dt][0] *= a0; acc[dt][1] *= a1;
            acc[dt][2] *= a2; acc[dt][3] *= a3;
        }

        // ---- PV: P via wave-private LDS round-trip (in-order, no barrier) ----
        bf16x8 pa = *(const bf16x8*)&Ps[(wave * 16 + li) * PSTR + QD * 8];
        #pragma unroll
        for (int dt = 0; dt < 4; dt++)
            acc[dt] = __builtin_amdgcn_mfma_f32_16x16x32_bf16(pa, vb[dt], acc[dt], 0, 0, 0);

        // ---- stage tile it+1 into the OTHER buffer (loads have landed) ----
        if (it + 1 < it_max) stage(p ^ 1);
    }

    // ---- epilogue: O /= l, fp32 store ----
    float invl = 1.0f / l_run;
    float i0 = __shfl(invl, QD * 4 + 0, 64);
    float i1 = __shfl(invl, QD * 4 + 1, 64);
    float i2 = __shfl(invl, QD * 4 + 2, 64);
    float i3 = __shfl(invl, QD * 4 + 3, 64);
    float* ob = out + boff + (size_t)q0 * DIM;
    const int rbase = wave * 16 + QD * 4;
    #pragma unroll
    for (int dt = 0; dt < 4; dt++) {
        int col = dt * 16 + li;
        ob[(size_t)(rbase + 0) * DIM + col] = acc[dt][0] * i0;
        ob[(size_t)(rbase + 1) * DIM + col] = acc[dt][1] * i1;
        ob[(size_t)(rbase + 2) * DIM + col] = acc[dt][2] * i2;
        ob[(size_t)(rbase + 3) * DIM + col] = acc[dt][3] * i3;
    }
}

extern "C" void kernel_launch(void* const* d_in, const int* in_sizes, int n_in,
                              void* d_out, int out_size, void* d_ws, size_t ws_size,
                              hipStream_t stream) {
    const float* q = (const float*)d_in[0];
    const float* k = (const float*)d_in[1];
    const float* v = (const float*)d_in[2];
    const int* valid_lens = (const int*)d_in[3];
    float* out = (float*)d_out;

    attn_mfma_flash6<<<dim3(BATCH * (SEQ / BQ)), dim3(256), 0, stream>>>(
        q, k, v, valid_lens, out);
}